// Round 13
// baseline (23.824 us; speedup 1.0000x reference)
//
#include <hip/hip_runtime.h>

#define NSAMP 65536
#define DTF 1e-5f

// packed complex: f2.x = re, f2.y = im ; ops lower to v_pk_fma_f32
typedef float f2 __attribute__((ext_vector_type(2)));

__device__ __forceinline__ f2 ib(f2 b) { return (f2){-b.y, b.x}; }

// acc += s*v with vn = ib(v): two packed FMAs (s = scalar side, v = vector side)
__device__ __forceinline__ f2 cmac_p(f2 acc, f2 s, f2 v, f2 vn) {
    acc = s.y * vn + acc;
    acc = s.x * v + acc;
    return acc;
}

// ---------- 4x4 complex matmul C = A*B (row-major, 16 f2), packed ----------
__device__ __forceinline__ void mm4p(const f2* A, const f2* B, f2* C) {
    f2 BN[16];
#pragma unroll
    for (int i = 0; i < 16; ++i) BN[i] = ib(B[i]);
#pragma unroll
    for (int a = 0; a < 4; ++a) {
#pragma unroll
        for (int b = 0; b < 4; ++b) {
            f2 acc = (f2){0.f, 0.f};
#pragma unroll
            for (int k = 0; k < 4; ++k)
                acc = cmac_p(acc, A[a * 4 + k], B[k * 4 + b], BN[k * 4 + b]);
            C[a * 4 + b] = acc;
        }
    }
}

// C = X*Y with XN = ib(X) PRECOMPUTED (X vector side, Y scalar side).
// Lets the swizzles hide under shfl/barrier latency instead of trailing them.
__device__ __forceinline__ void mm4p_Xf(const f2* X, const f2* XN, const f2* Y,
                                        f2* C) {
#pragma unroll
    for (int a = 0; a < 4; ++a) {
#pragma unroll
        for (int b = 0; b < 4; ++b) {
            f2 acc = (f2){0.f, 0.f};
#pragma unroll
            for (int k = 0; k < 4; ++k)
                acc = cmac_p(acc, Y[k * 4 + b], X[a * 4 + k], XN[a * 4 + k]);
            C[a * 4 + b] = acc;
        }
    }
}

// ---------- 16-f2 (128B) moves for 16B-aligned buffers ----------
__device__ __forceinline__ void ld16(f2* X, const f2* p) {
    const float4* q = (const float4*)p;
#pragma unroll
    for (int i = 0; i < 8; ++i) {
        float4 t = q[i];
        X[2 * i]     = (f2){t.x, t.y};
        X[2 * i + 1] = (f2){t.z, t.w};
    }
}
__device__ __forceinline__ void st16(f2* p, const f2* X) {
    float4* q = (float4*)p;
#pragma unroll
    for (int i = 0; i < 8; ++i)
        q[i] = make_float4(X[2 * i].x, X[2 * i].y, X[2 * i + 1].x, X[2 * i + 1].y);
}

// ---------- U = exp(-i*dt*H): order-6 Taylor via explicit powers ----------
// depth-3 mm4 chain: A2; {A3, A4}; {A5, A6}; FMA-folded sum.
__device__ __forceinline__ void expmU(float uxi, float uyi, float v1, float v2,
                                      float J, f2* X) {
    const float twopi = 6.2831855f;
    float d0 = twopi * (0.5f * (v1 + v2) + 0.25f * J);
    float d1 = twopi * (0.5f * (v1 - v2) - 0.25f * J);
    float d2 = twopi * (0.5f * (v2 - v1) - 0.25f * J);
    float d3 = twopi * (-0.5f * (v1 + v2) + 0.25f * J);
    float g  = twopi * 0.5f * J;
    float cr = 0.5f * uxi;
    float ci = -0.5f * uyi;

    f2 H[16];
    H[0]  = (f2){d0, 0.f};  H[1]  = (f2){cr, ci};
    H[2]  = (f2){cr, ci};   H[3]  = (f2){0.f, 0.f};
    H[4]  = (f2){cr, -ci};  H[5]  = (f2){d1, 0.f};
    H[6]  = (f2){g, 0.f};   H[7]  = (f2){cr, ci};
    H[8]  = (f2){cr, -ci};  H[9]  = (f2){g, 0.f};
    H[10] = (f2){d2, 0.f};  H[11] = (f2){cr, ci};
    H[12] = (f2){0.f, 0.f}; H[13] = (f2){cr, -ci};
    H[14] = (f2){cr, -ci};  H[15] = (f2){d3, 0.f};

    // A = -i * dt * H
    f2 A[16], AN[16];
#pragma unroll
    for (int k = 0; k < 16; ++k) {
        A[k]  = (f2){DTF * H[k].y, -DTF * H[k].x};
        AN[k] = ib(A[k]);
    }

    f2 A2[16], A2N[16];
    mm4p_Xf(A, AN, A, A2);            // depth 1
#pragma unroll
    for (int k = 0; k < 16; ++k) A2N[k] = ib(A2[k]);

    f2 A3[16], A4[16], A3N[16];
    mm4p_Xf(A, AN, A2, A3);           // depth 2 (A*A2)
    mm4p_Xf(A2, A2N, A2, A4);         // depth 2 (A2*A2) — independent of A3
#pragma unroll
    for (int k = 0; k < 16; ++k) A3N[k] = ib(A3[k]);

    f2 A5[16], A6[16];
    mm4p_Xf(A2, A2N, A3, A5);         // depth 3 (A2*A3)
    mm4p_Xf(A3, A3N, A3, A6);         // depth 3 (A3*A3) — independent of A5

    // X = I + A + A2/2 + A3/6 + A4/24 + A5/120 + A6/720 (FMA-folded)
#pragma unroll
    for (int k = 0; k < 16; ++k) {
        f2 t1 = A[k] + A2[k] * 0.5f;
        f2 t2 = A3[k] * (1.f / 6.f) + A4[k] * (1.f / 24.f);
        f2 t3 = A5[k] * (1.f / 120.f) + A6[k] * (1.f / 720.f);
        X[k] = t1 + t2 + t3;
    }
    X[0].x += 1.f; X[5].x += 1.f; X[10].x += 1.f; X[15].x += 1.f;
}

// ---------- barrier-free 64-lane inclusive matrix scan via shfl_up ----------
// Per round: XN=ib(X) issues BEFORE the 32 shuffles (independent -> hides
// under shfl latency); shuffled Y is the scalar side -> no dependent tail.
__device__ __forceinline__ void wave_scan(f2* X, int lane) {
#pragma unroll
    for (int off = 1; off < 64; off <<= 1) {
        f2 XN[16];
#pragma unroll
        for (int j = 0; j < 16; ++j) XN[j] = ib(X[j]);
        f2 Y[16];
#pragma unroll
        for (int j = 0; j < 16; ++j) {
            Y[j].x = __shfl_up(X[j].x, (unsigned)off, 64);
            Y[j].y = __shfl_up(X[j].y, (unsigned)off, 64);
        }
        if (lane >= off) {
            f2 Z[16];
            mm4p_Xf(X, XN, Y, Z);
#pragma unroll
            for (int j = 0; j < 16; ++j) X[j] = Z[j];
        }
    }
}

// tree-shaped cross-wave combine: depth 2 mm4; X-swizzles hide under barrier
__device__ __forceinline__ void block_combine(f2* X, f2 (*WT)[16],
                                              int w, int lane) {
    if (w < 3 && lane == 63) st16(&WT[w][0], X);
    f2 XN[16];
#pragma unroll
    for (int j = 0; j < 16; ++j) XN[j] = ib(X[j]); // hidden under barrier
    __syncthreads();
    if (w == 1) {
        f2 Y0[16], Z[16];
        ld16(Y0, &WT[0][0]);
        mm4p_Xf(X, XN, Y0, Z);
#pragma unroll
        for (int j = 0; j < 16; ++j) X[j] = Z[j];
    } else if (w == 2) {
        f2 Y1[16], Y0[16], Z1[16], Z[16];
        ld16(Y1, &WT[1][0]);
        ld16(Y0, &WT[0][0]);
        mm4p_Xf(X, XN, Y1, Z1);  // X*WT1
        mm4p(Z1, Y0, Z);         // (X*WT1)*WT0
#pragma unroll
        for (int j = 0; j < 16; ++j) X[j] = Z[j];
    } else if (w == 3) {
        f2 Y2[16], Y1[16], Y0[16], T1[16], T2[16], Z[16];
        ld16(Y2, &WT[2][0]);
        ld16(Y1, &WT[1][0]);
        ld16(Y0, &WT[0][0]);
        mm4p_Xf(X, XN, Y2, T1);  // X*WT2      (independent
        mm4p(Y1, Y0, T2);        // WT1*WT0     pair -> ILP)
        mm4p(T1, T2, Z);         // depth 2
#pragma unroll
        for (int j = 0; j < 16; ++j) X[j] = Z[j];
    }
}

// Re(a*conj(b))
__device__ __forceinline__ float rec(f2 a, f2 b) { return a.x * b.x + a.y * b.y; }
__device__ __forceinline__ float measure(const f2* wv) {
    float re0 = rec(wv[0], wv[1]) + rec(wv[0], wv[2]) +
                rec(wv[1], wv[3]) + rec(wv[2], wv[3]);
    float re3 = rec(wv[4], wv[5]) + rec(wv[4], wv[6]) +
                rec(wv[5], wv[7]) + rec(wv[6], wv[7]);
    return 0.25f * (re0 - re3);
}

// ---------- kA: expm + in-block scan; store S (float4 planes) + totals T ----------
__global__ __launch_bounds__(256) void kA_scan(
    const float* __restrict__ ux, const float* __restrict__ uy,
    const float* __restrict__ v1p, const float* __restrict__ v2p,
    const float* __restrict__ Jp, float4* __restrict__ S4,
    f2* __restrict__ T) {
    __shared__ __align__(16) f2 WT[3][16];
    int b = blockIdx.x, t = threadIdx.x;
    int lane = t & 63, w = t >> 6;
    int n = b * 256 + t;
    f2 X[16];
    expmU(ux[n], uy[n], *v1p, *v2p, *Jp, X);
    wave_scan(X, lane);
    block_combine(X, WT, w, lane); // X = U_n ... U_{256b}
#pragma unroll
    for (int q = 0; q < 8; ++q)
        S4[(size_t)q * NSAMP + n] =
            make_float4(X[2 * q].x, X[2 * q].y, X[2 * q + 1].x, X[2 * q + 1].y);
    if (t == 255) st16(T + (size_t)b * 16, X);
}

// ---------- kB: prefetch S (+swizzles); totals-scan -> prefix cols; apply ----------
__global__ __launch_bounds__(256) void kB_apply(
    const float4* __restrict__ S4, const f2* __restrict__ T,
    float* __restrict__ out) {
    __shared__ __align__(16) f2 WT[3][16];
    __shared__ __align__(16) f2 WB[8];
    int b = blockIdx.x, t = threadIdx.x;
    int lane = t & 63, w = t >> 6;
    int n = b * 256 + t;

    // prefetch in-block scan matrix; MN swizzles computed here so BOTH the
    // loads and the swizzles hide under the totals-scan below.
    f2 M[16], MN[16];
#pragma unroll
    for (int q = 0; q < 8; ++q) {
        float4 v = S4[(size_t)q * NSAMP + n];
        M[2 * q]     = (f2){v.x, v.y};
        M[2 * q + 1] = (f2){v.z, v.w};
    }
#pragma unroll
    for (int j = 0; j < 16; ++j) MN[j] = ib(M[j]);

    // scan the 256 block totals (32 KB, L2-resident) — every block redundantly
    f2 Xt[16];
    ld16(Xt, T + (size_t)t * 16);
    wave_scan(Xt, lane);
    block_combine(Xt, WT, w, lane); // thread t: T_t * ... * T_0
    if (b == 0) {
        if (t == 0) {
#pragma unroll
            for (int i = 0; i < 8; ++i) WB[i] = (f2){0.f, 0.f};
            WB[0] = (f2){1.f, 0.f}; // col0 of I
            WB[7] = (f2){1.f, 0.f}; // col3 of I
        }
    } else if (t == b - 1) { // inclusive at b-1 = exclusive prefix for block b
#pragma unroll
        for (int a = 0; a < 4; ++a) {
            WB[a]     = Xt[a * 4 + 0];
            WB[4 + a] = Xt[a * 4 + 3];
        }
    }
    __syncthreads();

    // apply: wv' = M * wv with M as the (preswizzled) vector side
    f2 wv[8];
#pragma unroll
    for (int i = 0; i < 8; ++i) wv[i] = WB[i];
    f2 r[8];
#pragma unroll
    for (int a = 0; a < 4; ++a) {
        f2 a0 = (f2){0.f, 0.f}, a1 = (f2){0.f, 0.f};
#pragma unroll
        for (int k = 0; k < 4; ++k) {
            a0 = cmac_p(a0, wv[k],     M[a * 4 + k], MN[a * 4 + k]);
            a1 = cmac_p(a1, wv[4 + k], M[a * 4 + k], MN[a * 4 + k]);
        }
        r[a] = a0;
        r[4 + a] = a1;
    }
    out[n] = measure(r);
}

extern "C" void kernel_launch(void* const* d_in, const int* in_sizes, int n_in,
                              void* d_out, int out_size, void* d_ws, size_t ws_size,
                              hipStream_t stream) {
    const float* ux = (const float*)d_in[0];
    const float* uy = (const float*)d_in[1];
    const float* v1 = (const float*)d_in[2];
    const float* v2 = (const float*)d_in[3];
    const float* J  = (const float*)d_in[4];
    float* out = (float*)d_out;

    char* ws = (char*)d_ws;
    // layout: S4 (8 planes * 65536 float4 = 8 MiB) | T (256 * 128B = 32 KiB)
    float4* S4 = (float4*)(ws);
    f2* T      = (f2*)(ws + (size_t)8 * NSAMP * 16);

    kA_scan<<<256, 256, 0, stream>>>(ux, uy, v1, v2, J, S4, T);
    kB_apply<<<256, 256, 0, stream>>>(S4, T, out);
}

// Round 14
// 22.648 us; speedup vs baseline: 1.0519x; 1.0519x over previous
//
#include <hip/hip_runtime.h>

#define NSAMP 65536
#define DTF 1e-5f

// packed complex: f2.x = re, f2.y = im ; ops lower to v_pk_fma_f32
typedef float f2 __attribute__((ext_vector_type(2)));

__device__ __forceinline__ f2 ib(f2 b) { return (f2){-b.y, b.x}; }

// acc += a*b with bn = ib(b): two packed FMAs (a = scalar side)
__device__ __forceinline__ f2 cmac_p(f2 acc, f2 a, f2 b, f2 bn) {
    acc = a.y * bn + acc;
    acc = a.x * b + acc;
    return acc;
}

// ---------- 4x4 complex matmul C = A*B (row-major, 16 f2), packed ----------
__device__ __forceinline__ void mm4p(const f2* A, const f2* B, f2* C) {
    f2 BN[16];
#pragma unroll
    for (int i = 0; i < 16; ++i) BN[i] = ib(B[i]);
#pragma unroll
    for (int a = 0; a < 4; ++a) {
#pragma unroll
        for (int b = 0; b < 4; ++b) {
            f2 acc = (f2){0.f, 0.f};
#pragma unroll
            for (int k = 0; k < 4; ++k)
                acc = cmac_p(acc, A[a * 4 + k], B[k * 4 + b], BN[k * 4 + b]);
            C[a * 4 + b] = acc;
        }
    }
}

// C = A*X with A's swizzles precomputed (AN = ib(A)); X is the scalar side
__device__ __forceinline__ void mm4p_Af(const f2* A, const f2* AN, const f2* X,
                                        f2* C) {
#pragma unroll
    for (int a = 0; a < 4; ++a) {
#pragma unroll
        for (int b = 0; b < 4; ++b) {
            f2 acc = (f2){0.f, 0.f};
#pragma unroll
            for (int k = 0; k < 4; ++k)
                acc = cmac_p(acc, X[k * 4 + b], A[a * 4 + k], AN[a * 4 + k]);
            C[a * 4 + b] = acc;
        }
    }
}

// two matvecs: w[0..3] <- M*w[0..3], w[4..7] <- M*w[4..7] (packed)
__device__ __forceinline__ void mv2p(const f2* M, f2* w) {
    f2 WN[8];
#pragma unroll
    for (int i = 0; i < 8; ++i) WN[i] = ib(w[i]);
    f2 r[8];
#pragma unroll
    for (int a = 0; a < 4; ++a) {
        f2 a0 = (f2){0.f, 0.f}, a1 = (f2){0.f, 0.f};
#pragma unroll
        for (int k = 0; k < 4; ++k) {
            a0 = cmac_p(a0, M[a * 4 + k], w[k], WN[k]);
            a1 = cmac_p(a1, M[a * 4 + k], w[4 + k], WN[4 + k]);
        }
        r[a] = a0;
        r[4 + a] = a1;
    }
#pragma unroll
    for (int i = 0; i < 8; ++i) w[i] = r[i];
}

// ---------- 16-f2 (128B) moves for 16B-aligned buffers ----------
__device__ __forceinline__ void ld16(f2* X, const f2* p) {
    const float4* q = (const float4*)p;
#pragma unroll
    for (int i = 0; i < 8; ++i) {
        float4 t = q[i];
        X[2 * i]     = (f2){t.x, t.y};
        X[2 * i + 1] = (f2){t.z, t.w};
    }
}
__device__ __forceinline__ void st16(f2* p, const f2* X) {
    float4* q = (float4*)p;
#pragma unroll
    for (int i = 0; i < 8; ++i)
        q[i] = make_float4(X[2 * i].x, X[2 * i].y, X[2 * i + 1].x, X[2 * i + 1].y);
}

// ---------- U = exp(-i*dt*H): order-6 Taylor via explicit powers ----------
// depth-3 mm4 chain (vs Horner's 5): A2; {A3, A4}; {A5, A6}; FMA-folded sum.
__device__ __forceinline__ void expmU(float uxi, float uyi, float v1, float v2,
                                      float J, f2* X) {
    const float twopi = 6.2831855f;
    float d0 = twopi * (0.5f * (v1 + v2) + 0.25f * J);
    float d1 = twopi * (0.5f * (v1 - v2) - 0.25f * J);
    float d2 = twopi * (0.5f * (v2 - v1) - 0.25f * J);
    float d3 = twopi * (-0.5f * (v1 + v2) + 0.25f * J);
    float g  = twopi * 0.5f * J;
    float cr = 0.5f * uxi;
    float ci = -0.5f * uyi;

    f2 H[16];
    H[0]  = (f2){d0, 0.f};  H[1]  = (f2){cr, ci};
    H[2]  = (f2){cr, ci};   H[3]  = (f2){0.f, 0.f};
    H[4]  = (f2){cr, -ci};  H[5]  = (f2){d1, 0.f};
    H[6]  = (f2){g, 0.f};   H[7]  = (f2){cr, ci};
    H[8]  = (f2){cr, -ci};  H[9]  = (f2){g, 0.f};
    H[10] = (f2){d2, 0.f};  H[11] = (f2){cr, ci};
    H[12] = (f2){0.f, 0.f}; H[13] = (f2){cr, -ci};
    H[14] = (f2){cr, -ci};  H[15] = (f2){d3, 0.f};

    // A = -i * dt * H
    f2 A[16], AN[16];
#pragma unroll
    for (int k = 0; k < 16; ++k) {
        A[k]  = (f2){DTF * H[k].y, -DTF * H[k].x};
        AN[k] = ib(A[k]);
    }

    f2 A2[16], A2N[16];
    mm4p_Af(A, AN, A, A2);            // depth 1
#pragma unroll
    for (int k = 0; k < 16; ++k) A2N[k] = ib(A2[k]);

    f2 A3[16], A4[16], A3N[16];
    mm4p_Af(A, AN, A2, A3);           // depth 2 (A*A2)
    mm4p_Af(A2, A2N, A2, A4);         // depth 2 (A2*A2) — independent of A3
#pragma unroll
    for (int k = 0; k < 16; ++k) A3N[k] = ib(A3[k]);

    f2 A5[16], A6[16];
    mm4p_Af(A2, A2N, A3, A5);         // depth 3 (A2*A3)
    mm4p_Af(A3, A3N, A3, A6);         // depth 3 (A3*A3) — independent of A5

    // X = I + A + A2/2 + A3/6 + A4/24 + A5/120 + A6/720 (FMA-folded)
#pragma unroll
    for (int k = 0; k < 16; ++k) {
        f2 t1 = A[k] + A2[k] * 0.5f;
        f2 t2 = A3[k] * (1.f / 6.f) + A4[k] * (1.f / 24.f);
        f2 t3 = A5[k] * (1.f / 120.f) + A6[k] * (1.f / 720.f);
        X[k] = t1 + t2 + t3;
    }
    X[0].x += 1.f; X[5].x += 1.f; X[10].x += 1.f; X[15].x += 1.f;
}

// ---------- barrier-free 64-lane inclusive matrix scan via shfl_up ----------
__device__ __forceinline__ void wave_scan(f2* X, int lane) {
#pragma unroll
    for (int off = 1; off < 64; off <<= 1) {
        f2 Y[16];
#pragma unroll
        for (int j = 0; j < 16; ++j) {
            Y[j].x = __shfl_up(X[j].x, (unsigned)off, 64);
            Y[j].y = __shfl_up(X[j].y, (unsigned)off, 64);
        }
        if (lane >= off) {
            f2 Z[16];
            mm4p(X, Y, Z);
#pragma unroll
            for (int j = 0; j < 16; ++j) X[j] = Z[j];
        }
    }
}

// tree-shaped cross-wave combine: depth 2 mm4 (was 3 progressive)
__device__ __forceinline__ void block_combine(f2* X, f2 (*WT)[16],
                                              int w, int lane) {
    if (w < 3 && lane == 63) st16(&WT[w][0], X);
    __syncthreads();
    if (w == 1) {
        f2 Y0[16], Z[16];
        ld16(Y0, &WT[0][0]);
        mm4p(X, Y0, Z);
#pragma unroll
        for (int j = 0; j < 16; ++j) X[j] = Z[j];
    } else if (w == 2) {
        f2 Y1[16], Y0[16], Z1[16], Z[16];
        ld16(Y1, &WT[1][0]);
        ld16(Y0, &WT[0][0]);
        mm4p(X, Y1, Z1);       // X*WT1
        mm4p(Z1, Y0, Z);       // (X*WT1)*WT0
#pragma unroll
        for (int j = 0; j < 16; ++j) X[j] = Z[j];
    } else if (w == 3) {
        f2 Y2[16], Y1[16], Y0[16], T1[16], T2[16], Z[16];
        ld16(Y2, &WT[2][0]);
        ld16(Y1, &WT[1][0]);
        ld16(Y0, &WT[0][0]);
        mm4p(X, Y2, T1);       // X*WT2      (independent
        mm4p(Y1, Y0, T2);      // WT1*WT0     pair -> ILP)
        mm4p(T1, T2, Z);       // depth 2
#pragma unroll
        for (int j = 0; j < 16; ++j) X[j] = Z[j];
    }
}

// Re(a*conj(b))
__device__ __forceinline__ float rec(f2 a, f2 b) { return a.x * b.x + a.y * b.y; }
__device__ __forceinline__ float measure(const f2* wv) {
    float re0 = rec(wv[0], wv[1]) + rec(wv[0], wv[2]) +
                rec(wv[1], wv[3]) + rec(wv[2], wv[3]);
    float re3 = rec(wv[4], wv[5]) + rec(wv[4], wv[6]) +
                rec(wv[5], wv[7]) + rec(wv[6], wv[7]);
    return 0.25f * (re0 - re3);
}

// ---------- kA: expm + in-block scan; store S (float4 planes) + totals T ----------
__global__ __launch_bounds__(256) void kA_scan(
    const float* __restrict__ ux, const float* __restrict__ uy,
    const float* __restrict__ v1p, const float* __restrict__ v2p,
    const float* __restrict__ Jp, float4* __restrict__ S4,
    f2* __restrict__ T) {
    __shared__ __align__(16) f2 WT[3][16];
    int b = blockIdx.x, t = threadIdx.x;
    int lane = t & 63, w = t >> 6;
    int n = b * 256 + t;
    f2 X[16];
    expmU(ux[n], uy[n], *v1p, *v2p, *Jp, X);
    wave_scan(X, lane);
    block_combine(X, WT, w, lane); // X = U_n ... U_{256b}
#pragma unroll
    for (int q = 0; q < 8; ++q)
        S4[(size_t)q * NSAMP + n] =
            make_float4(X[2 * q].x, X[2 * q].y, X[2 * q + 1].x, X[2 * q + 1].y);
    if (t == 255) st16(T + (size_t)b * 16, X);
}

// ---------- kB: prefetch S; redundant totals-scan -> prefix cols; apply ----------
__global__ __launch_bounds__(256) void kB_apply(
    const float4* __restrict__ S4, const f2* __restrict__ T,
    float* __restrict__ out) {
    __shared__ __align__(16) f2 WT[3][16];
    __shared__ __align__(16) f2 WB[8];
    int b = blockIdx.x, t = threadIdx.x;
    int lane = t & 63, w = t >> 6;
    int n = b * 256 + t;

    // prefetch this sample's in-block scan matrix NOW; consumed after the
    // totals-scan (~9 mm4 rounds) -> HBM/L2 latency fully hidden.
    f2 M[16];
#pragma unroll
    for (int q = 0; q < 8; ++q) {
        float4 v = S4[(size_t)q * NSAMP + n];
        M[2 * q]     = (f2){v.x, v.y};
        M[2 * q + 1] = (f2){v.z, v.w};
    }

    // scan the 256 block totals (32 KB, L2-resident) — every block redundantly
    f2 Xt[16];
    ld16(Xt, T + (size_t)t * 16);
    wave_scan(Xt, lane);
    block_combine(Xt, WT, w, lane); // thread t: T_t * ... * T_0
    if (b == 0) {
        if (t == 0) {
#pragma unroll
            for (int i = 0; i < 8; ++i) WB[i] = (f2){0.f, 0.f};
            WB[0] = (f2){1.f, 0.f}; // col0 of I
            WB[7] = (f2){1.f, 0.f}; // col3 of I
        }
    } else if (t == b - 1) { // inclusive at b-1 = exclusive prefix for block b
#pragma unroll
        for (int a = 0; a < 4; ++a) {
            WB[a]     = Xt[a * 4 + 0];
            WB[4 + a] = Xt[a * 4 + 3];
        }
    }
    __syncthreads();

    // apply prefix cols to in-block matrix, measure
    f2 wv[8];
#pragma unroll
    for (int i = 0; i < 8; ++i) wv[i] = WB[i];
    mv2p(M, wv); // cols 0,3 of inclusive product P_n
    out[n] = measure(wv);
}

extern "C" void kernel_launch(void* const* d_in, const int* in_sizes, int n_in,
                              void* d_out, int out_size, void* d_ws, size_t ws_size,
                              hipStream_t stream) {
    const float* ux = (const float*)d_in[0];
    const float* uy = (const float*)d_in[1];
    const float* v1 = (const float*)d_in[2];
    const float* v2 = (const float*)d_in[3];
    const float* J  = (const float*)d_in[4];
    float* out = (float*)d_out;

    char* ws = (char*)d_ws;
    // layout: S4 (8 planes * 65536 float4 = 8 MiB) | T (256 * 128B = 32 KiB)
    float4* S4 = (float4*)(ws);
    f2* T      = (f2*)(ws + (size_t)8 * NSAMP * 16);

    kA_scan<<<256, 256, 0, stream>>>(ux, uy, v1, v2, J, S4, T);
    kB_apply<<<256, 256, 0, stream>>>(S4, T, out);
}